// Round 12
// baseline (333.922 us; speedup 1.0000x reference)
//
#include <hip/hip_runtime.h>
#include <cstdint>

#define TEMP_C 20.0f

typedef float f32x4 __attribute__((ext_vector_type(4)));
typedef float f32x16 __attribute__((ext_vector_type(16)));
typedef int i32x4 __attribute__((ext_vector_type(4)));
typedef int i32x8 __attribute__((ext_vector_type(8)));

// fp32 -> bf16 round-to-nearest-even
__device__ __forceinline__ unsigned short f2bf(float f) {
  union { float f; unsigned int u; } v; v.f = f;
  unsigned int r = v.u + 0x7FFFu + ((v.u >> 16) & 1u);
  return (unsigned short)(r >> 16);
}
__device__ __forceinline__ float bf2f(unsigned short b) {
  union { unsigned int u; float f; } v; v.u = ((unsigned int)b) << 16;
  return v.f;
}

// fp32 -> OCP e4m3fn, RTNE, clamp to +-448
__device__ __forceinline__ unsigned char f2e4m3(float f) {
  unsigned u = __float_as_uint(f);
  unsigned s = (u >> 24) & 0x80u;
  float a = fminf(fabsf(f), 448.0f);
  if (a < 0.015625f) {
    int d = (int)rintf(a * 512.0f);
    return (unsigned char)(s | (unsigned)d);
  }
  unsigned au = __float_as_uint(a);
  unsigned r = au + 0xFFFFFu + ((au >> 20) & 1u);
  int Ep = (int)(r >> 23) - 127;
  if (Ep > 8) return (unsigned char)(s | 0x7E);
  unsigned m = (r >> 20) & 7u;
  return (unsigned char)(s | ((unsigned)(Ep + 7) << 3) | m);
}

// async global->LDS, 16B per lane (dest = wave-uniform base + lane*16)
__device__ __forceinline__ void gload_lds16(const void* g, void* l) {
  __builtin_amdgcn_global_load_lds(
      (__attribute__((address_space(1))) void*)(g),
      (__attribute__((address_space(3))) void*)(l), 16, 0, 0);
}

// ---------------------------------------------------------------------------
// 1a) partial sum-of-squares, all 6 slices, FLOAT4-vectorized over pixels.
//     thread (f4 lane6, channel-sub) accumulates 4 pixel sums over cpc/4 chans.
struct Src6 { const float* p[6]; };

__global__ __launch_bounds__(256) void colnorm_part6_k(
    Src6 S, float* __restrict__ part)
{
  const int sl = blockIdx.z;
  const float* __restrict__ X = S.p[sl];
  const int C = (sl < 3) ? 2048 : 1024;
  const int cpc = C >> 4;                 // 16 chunks
  __shared__ f32x4 red[4][64];
  const int lane6 = threadIdx.x & 63;
  const int sub = threadIdx.x >> 6;
  const int fi = blockIdx.x * 64 + lane6;   // float4 index (3600/4 = 900)
  const int c0 = blockIdx.y * cpc;
  f32x4 s = {0.f, 0.f, 0.f, 0.f};
  if (fi < 900) {
    const f32x4* Xv = (const f32x4*)X;
    for (int c = c0 + sub; c < c0 + cpc; c += 4) {
      f32x4 v = Xv[(size_t)c * 900 + fi];
      s += v * v;
    }
  }
  red[sub][lane6] = s;
  __syncthreads();
  if (sub == 0 && fi < 900) {
    f32x4 t = red[0][lane6] + red[1][lane6] + red[2][lane6] + red[3][lane6];
    *(f32x4*)&part[(size_t)(sl * 16 + blockIdx.y) * 3600 + fi * 4] = t;
  }
}

// 1b) finish all 6 slices (float4)
__global__ __launch_bounds__(256) void colnorm_fin6_k(
    const float* __restrict__ part, float* __restrict__ invn)
{
  const int z = blockIdx.y;
  const int fi = blockIdx.x * 256 + threadIdx.x;
  if (fi >= 900) return;
  const f32x4* pv = (const f32x4*)part;
  f32x4 s = {0.f, 0.f, 0.f, 0.f};
  #pragma unroll
  for (int j = 0; j < 16; ++j) s += pv[(size_t)(z * 16 + j) * 900 + fi];
  f32x4 r;
  #pragma unroll
  for (int e = 0; e < 4; ++e) r[e] = 1.0f / fmaxf(sqrtf(s[e]), 1e-12f);
  *(f32x4*)&invn[(size_t)z * 3600 + fi * 4] = r;
}

// ---------------------------------------------------------------------------
// 2) fused transpose+scale+FP8 cast, K-GROUP-MAJOR: T[(g*3840+p)*16 + (col&15)]
__global__ __launch_bounds__(256) void tpose2_f8_k(
    const float* __restrict__ X4, const float* __restrict__ X3,
    const float* __restrict__ i4, const float* __restrict__ i3,
    const float* __restrict__ wch, int usew, unsigned char* __restrict__ T)
{
  __shared__ float tile[32][33];
  const int tx = threadIdx.x, ty = threadIdx.y;
  const int y = blockIdx.y;
  const float* X; const float* inv; int c0, cdst; float mult;
  if (y < 64) { X = X4; inv = i4; c0 = y * 32;        cdst = c0;        mult = usew ? TEMP_C * wch[0] * 0.25f : 4.0f; }
  else        { X = X3; inv = i3; c0 = (y - 64) * 32; cdst = 2048 + c0; mult = usew ? TEMP_C * wch[1] * 0.25f : 4.0f; }
  const int p0 = blockIdx.x * 32;
  #pragma unroll
  for (int i = 0; i < 4; ++i) {
    int c = c0 + ty + i * 8, p = p0 + tx;
    tile[ty + i * 8][tx] = (p < 3600) ? X[(size_t)c * 3600 + p] : 0.f;
  }
  __syncthreads();
  const int col = cdst + tx;
  const size_t gbase = (size_t)(col >> 4) * 3840 * 16 + (col & 15);
  #pragma unroll
  for (int i = 0; i < 4; ++i) {
    int p = p0 + ty + i * 8;
    if (p < 3600) {
      float sc = inv[p] * mult;
      T[gbase + (size_t)p * 16] = f2e4m3(tile[tx][ty + i * 8] * sc);
    }
  }
}

// ---------------------------------------------------------------------------
// 3) V cast to fp8, K-group-major over s: V8[((s>>4)*512 + c)*16 + (s&15)]
__global__ void castv_f8_k(const float* __restrict__ X, unsigned char* __restrict__ V8)
{
  int i = blockIdx.x * 256 + threadIdx.x;
  if (i >= 512 * 3600) return;
  int c = i / 3600, s = i - c * 3600;
  V8[((size_t)(s >> 4) * 512 + c) * 16 + (s & 15)] = f2e4m3(X[i]);
}

// ---------------------------------------------------------------------------
// helpers for the GEMM fragment loads
__device__ __forceinline__ i32x8 ld8_pair(const unsigned char* p, long stride) {
  i32x4 lo = *(const i32x4*)p;
  i32x4 hi = *(const i32x4*)(p + stride);
  i32x8 r;
  r[0]=lo[0]; r[1]=lo[1]; r[2]=lo[2]; r[3]=lo[3];
  r[4]=hi[0]; r[5]=hi[1]; r[6]=hi[2]; r[7]=hi[3];
  return r;
}

// ---------------------------------------------------------------------------
// 4) 128x128 MX-fp8 correlation GEMM. A: LDS-staged (16KB, 2 slots).
//    B: DIRECT global->VGPR (K-group-major => 2x512B contiguous per b128 —
//    coalesced L2 hits), register double-buffered via unroll-by-2 with NAMED
//    regs (rule #20). Per tile per wave: 2 gload_lds + 4 global b128 = 6 vmem
//    -> counted vmcnt(6) waits only tile t's batch (issued a full tile ago).
//    LDS reads/tile halved (4 b128). Output bf16.
__global__ __launch_bounds__(256, 3) void gemm128_f8(
    const unsigned char* __restrict__ A, const unsigned char* __restrict__ B,
    unsigned short* __restrict__ C, int K, int MPr, int ldc, int nbn)
{
  __shared__ __align__(16) unsigned char As[2][8192];   // [4 g][128 rows][16B]

  const int tid  = threadIdx.x;
  const int lane = tid & 63;
  const int wave = tid >> 6;     // 0..3
  const int wrow = wave >> 1;    // 0..1 (M half)
  const int wcol = wave & 1;     // 0..1 (N half)

  // XCD-aware bijective block remap (m204)
  const int nwg = gridDim.x;
  const int q8 = nwg >> 3, r8 = nwg & 7;
  const int xcd = blockIdx.x & 7, bidx = blockIdx.x >> 3;
  const int wg = (xcd < r8 ? xcd * (q8 + 1) : r8 * (q8 + 1) + (xcd - r8) * q8) + bidx;
  const long Arow0 = (long)(wg / nbn) * 128;
  const long Brow0 = (long)(wg % nbn) * 128;

  // A staging: thread owns chunks c = tid (g=tid>>7), 256+tid (g=2+(tid>>7))
  const unsigned char* sA0 = A + ((long)(tid >> 7) * MPr + Arow0 + (tid & 127)) * 16;
  const unsigned char* sA1 = A + ((long)(2 + (tid >> 7)) * MPr + Arow0 + (tid & 127)) * 16;
  const long kstride = (long)MPr * 16 * 4;   // 4 groups per K-tile (BK=64)

  #define STAGE_A(tt) do { const int _sl = (tt) & 1; const long _ko = (long)(tt) * kstride; \
    gload_lds16(sA0 + _ko, &As[_sl][tid * 16]);              \
    gload_lds16(sA1 + _ko, &As[_sl][(256 + tid) * 16]);      \
  } while (0)

  const int l31 = lane & 31, lk = lane >> 5;
  const int arow0 = (wrow * 64 + l31) * 16;   // m-tile 0; m=1 at +512
  const long ksg = (long)MPr * 16;            // one k-group stride in B
  // B per-lane base: groups lk*2 + {0,1}, rows Brow0 + wcol*64 + nt*32 + l31
  const unsigned char* pB = B + ((long)(lk * 2) * MPr + Brow0 + wcol * 64 + l31) * 16;

  #define LDA8(sl_, mb) ld8_pair(&As[sl_][((lk * 2) << 11) + arow0 + (mb)], 2048)
  #define MFMA8(a, b, m, n) \
    acc[m][n] = __builtin_amdgcn_mfma_scale_f32_32x32x64_f8f6f4( \
        a, b, acc[m][n], 0, 0, 0, 127, 0, 127)
  #define BAR   asm volatile("s_barrier" ::: "memory")
  #define LGKM0 do { asm volatile("s_waitcnt lgkmcnt(0)" ::: "memory");    \
                     __builtin_amdgcn_sched_barrier(0); } while (0)

  f32x16 acc[2][2] = {};
  const int NT = K >> 6;   // 48 (even)

  // prologue: tile 0 -> A stage + B regs (6 vmem outstanding)
  STAGE_A(0);
  i32x8 Bc0 = ld8_pair(pB, ksg);
  i32x8 Bc1 = ld8_pair(pB + 512, ksg);
  i32x8 Bn0, Bn1;

  for (int t = 0; t < NT; t += 2) {
    // ---- even tile t (slot 0): prefetch t+1, compute with Bc*
    STAGE_A(t + 1);
    { const unsigned char* _p = pB + (long)(t + 1) * kstride;
      Bn0 = ld8_pair(_p, ksg); Bn1 = ld8_pair(_p + 512, ksg); }
    asm volatile("s_waitcnt vmcnt(6)" ::: "memory");   // tile t's 6 landed
    BAR;
    {
      i32x8 a0 = LDA8(0, 0), a1 = LDA8(0, 512);
      LGKM0;
      __builtin_amdgcn_s_setprio(1);
      MFMA8(a0, Bc0, 0, 0); MFMA8(a0, Bc1, 0, 1);
      MFMA8(a1, Bc0, 1, 0); MFMA8(a1, Bc1, 1, 1);
      __builtin_amdgcn_s_setprio(0);
    }
    BAR;

    // ---- odd tile t+1 (slot 1): prefetch t+2, compute with Bn*
    if (t + 2 < NT) {
      STAGE_A(t + 2);
      const unsigned char* _p = pB + (long)(t + 2) * kstride;
      Bc0 = ld8_pair(_p, ksg); Bc1 = ld8_pair(_p + 512, ksg);
      asm volatile("s_waitcnt vmcnt(6)" ::: "memory");
    } else {
      asm volatile("s_waitcnt vmcnt(0)" ::: "memory");
    }
    BAR;
    {
      i32x8 a0 = LDA8(1, 0), a1 = LDA8(1, 512);
      LGKM0;
      __builtin_amdgcn_s_setprio(1);
      MFMA8(a0, Bn0, 0, 0); MFMA8(a0, Bn1, 0, 1);
      MFMA8(a1, Bn0, 1, 0); MFMA8(a1, Bn1, 1, 1);
      __builtin_amdgcn_s_setprio(0);
    }
    BAR;
  }
  #undef STAGE_A
  #undef LDA8
  #undef MFMA8
  #undef BAR
  #undef LGKM0

  // epilogue (bf16): col=lane&31, row = (reg&3) + 8*(reg>>2) + 4*(lane>>5)
  #pragma unroll
  for (int m = 0; m < 2; ++m) {
    const long rowb = Arow0 + wrow * 64 + m * 32;
    #pragma unroll
    for (int g4 = 0; g4 < 4; ++g4) {
      #pragma unroll
      for (int r4 = 0; r4 < 4; ++r4) {
        const long row = rowb + r4 + 8 * g4 + 4 * lk;
        unsigned short* cp = C + row * (long)ldc + Brow0 + wcol * 64 + l31;
        cp[0]  = f2bf(acc[m][0][g4 * 4 + r4]);
        cp[32] = f2bf(acc[m][1][g4 * 4 + r4]);
      }
    }
  }
}

// ---------------------------------------------------------------------------
// 5) PV MX-fp8 GEMM (round 10, verified): P[z][q][c] (+)= Att8[q][s]*V8[c][s].
__global__ __launch_bounds__(256, 2) void pv_f8_k(
    const unsigned char* __restrict__ Att, const unsigned char* __restrict__ V,
    unsigned short* __restrict__ P, int accumulate)
{
  __shared__ __align__(16) unsigned char As[2][128 * 128];
  __shared__ __align__(16) unsigned char Bs[2][128 * 128];

  const int tid  = threadIdx.x;
  const int lane = tid & 63;
  const int wave = tid >> 6;
  const int wrow = wave >> 1;
  const int wcol = wave & 1;
  const long Arow0 = (long)blockIdx.x * 128;   // q
  const long Brow0 = (long)blockIdx.y * 128;   // c
  const int z = blockIdx.z;
  P += (long)z * 3840 * 512;

  const unsigned char* sA[4];
  const unsigned char* sB[4];
  #pragma unroll
  for (int q = 0; q < 4; ++q) {
    const int c = q * 256 + tid;
    const int g = c >> 7, r = c & 127;
    sA[q] = Att + ((long)(z * 40 + g) * 3840 + Arow0 + r) * 16;
    sB[q] = V   + ((long)(z * 40 + g) * 512  + Brow0 + r) * 16;
  }
  const long ksA = 3840L * 16 * 8;
  const long ksB = 512L * 16 * 8;

  #define STAGE(tt) do { const int _sl = (tt) & 1;                          \
    _Pragma("unroll")                                                       \
    for (int q = 0; q < 4; ++q)                                             \
      gload_lds16(sA[q] + (long)(tt) * ksA, &As[_sl][(q * 256 + tid) * 16]);\
    _Pragma("unroll")                                                       \
    for (int q = 0; q < 4; ++q)                                             \
      gload_lds16(sB[q] + (long)(tt) * ksB, &Bs[_sl][(q * 256 + tid) * 16]);\
  } while (0)

  const int l31 = lane & 31, lk = lane >> 5;
  const int arow0 = (wrow * 64 + l31) * 16;
  const int brow0 = (wcol * 64 + l31) * 16;

  f32x16 acc[2][2] = {};
  const int NT = 5;

  STAGE(0);

  for (int t = 0; t < NT; ++t) {
    const int sl = t & 1;
    if (t + 1 < NT) {
      STAGE(t + 1);
      asm volatile("s_waitcnt vmcnt(8)" ::: "memory");
    } else {
      asm volatile("s_waitcnt vmcnt(0)" ::: "memory");
    }
    asm volatile("s_barrier" ::: "memory");

    const unsigned char* Ap = As[sl];
    const unsigned char* Bp = Bs[sl];
    #define LDF(base, rowb, h, s) \
      (*(const i32x4*)((base) + ((((h) * 4 + lk * 2 + (s)) << 11) + (rowb))))
    #define FRAG(dst, base, rowb, h) do {               \
      i32x4 _lo = LDF(base, rowb, h, 0);                \
      i32x4 _hi = LDF(base, rowb, h, 1);                \
      dst[0]=_lo[0]; dst[1]=_lo[1]; dst[2]=_lo[2]; dst[3]=_lo[3]; \
      dst[4]=_hi[0]; dst[5]=_hi[1]; dst[6]=_hi[2]; dst[7]=_hi[3]; \
    } while (0)
    #define MFMA8(a, b, m, n) \
      acc[m][n] = __builtin_amdgcn_mfma_scale_f32_32x32x64_f8f6f4( \
          a, b, acc[m][n], 0, 0, 0, 127, 0, 127)

    #pragma unroll
    for (int h = 0; h < 2; ++h) {
      i32x8 a0, a1, b0, b1;
      FRAG(a0, Ap, arow0, h); FRAG(a1, Ap, arow0 + 512, h);
      FRAG(b0, Bp, brow0, h); FRAG(b1, Bp, brow0 + 512, h);
      __builtin_amdgcn_s_setprio(1);
      MFMA8(a0, b0, 0, 0); MFMA8(a0, b1, 0, 1);
      MFMA8(a1, b0, 1, 0); MFMA8(a1, b1, 1, 1);
      __builtin_amdgcn_s_setprio(0);
    }
    #undef LDF
    #undef FRAG
    #undef MFMA8
    asm volatile("s_barrier" ::: "memory");
  }
  #undef STAGE

  #pragma unroll
  for (int m = 0; m < 2; ++m) {
    const long rowb = Arow0 + wrow * 64 + m * 32;
    #pragma unroll
    for (int g4 = 0; g4 < 4; ++g4) {
      #pragma unroll
      for (int r4 = 0; r4 < 4; ++r4) {
        const long row = rowb + r4 + 8 * g4 + 4 * lk;
        unsigned short* cp = P + row * 512 + Brow0 + wcol * 64 + l31;
        float v0 = acc[m][0][g4 * 4 + r4];
        float v1 = acc[m][1][g4 * 4 + r4];
        if (accumulate) { v0 += bf2f(cp[0]); v1 += bf2f(cp[32]); }
        cp[0]  = f2bf(v0);
        cp[32] = f2bf(v1);
      }
    }
  }
}

// ---------------------------------------------------------------------------
// 6) row softmax: reads bf16 logits, writes fp8 attn*448 K-group-major
__global__ __launch_bounds__(256) void softmax_rows_k(
    const unsigned short* __restrict__ Lb, unsigned char* __restrict__ Att)
{
  const int q = blockIdx.x;
  const unsigned short* row = Lb + (size_t)q * 3840;
  const int tid = threadIdx.x;
  float v[15];
  float mx = -1e30f;
  #pragma unroll
  for (int j = 0; j < 15; ++j) {
    int s = tid + j * 256;
    float x = (s < 3600) ? bf2f(row[s]) : -1e30f;
    v[j] = x;
    mx = fmaxf(mx, x);
  }
  #pragma unroll
  for (int o = 32; o > 0; o >>= 1) mx = fmaxf(mx, __shfl_xor(mx, o));
  __shared__ float wmax[4], wsum[4];
  if ((tid & 63) == 0) wmax[tid >> 6] = mx;
  __syncthreads();
  mx = fmaxf(fmaxf(wmax[0], wmax[1]), fmaxf(wmax[2], wmax[3]));
  float sum = 0.f;
  #pragma unroll
  for (int j = 0; j < 15; ++j) {
    int s = tid + j * 256;
    float e = (s < 3600) ? __expf(v[j] - mx) : 0.f;
    v[j] = e;
    sum += e;
  }
  #pragma unroll
  for (int o = 32; o > 0; o >>= 1) sum += __shfl_xor(sum, o);
  if ((tid & 63) == 0) wsum[tid >> 6] = sum;
  __syncthreads();
  sum = wsum[0] + wsum[1] + wsum[2] + wsum[3];
  const float inv448 = 448.0f / sum;
  #pragma unroll
  for (int j = 0; j < 15; ++j) {
    int s = tid + j * 256;
    unsigned char b = (s < 3600) ? f2e4m3(v[j] * inv448) : (unsigned char)0;
    Att[((size_t)(s >> 4) * 3840 + q) * 16 + (s & 15)] = b;
  }
}

// ---------------------------------------------------------------------------
// 7) out[c][p] = 0.5*f_q[c][p] + (0.25/448)*sum_z P[z][p][c]  (bf16 partials)
__global__ __launch_bounds__(256) void final_blend_k(
    const unsigned short* __restrict__ P, const float* __restrict__ fq,
    float* __restrict__ out)
{
  __shared__ float t[32][33];
  const int tx = threadIdx.x, ty = threadIdx.y;
  const int p0 = blockIdx.x * 32, c0 = blockIdx.y * 32;
  const long ZC = 3840L * 512;
  #pragma unroll
  for (int i = 0; i < 4; ++i) {
    int p = p0 + ty + i * 8, c = c0 + tx;
    float s = 0.f;
    if (p < 3600) {
      size_t o = (size_t)p * 512 + c;
      #pragma unroll
      for (int z = 0; z < 6; ++z) s += bf2f(P[o + (size_t)z * ZC]);
    }
    t[ty + i * 8][tx] = s;
  }
  __syncthreads();
  const float wts = 0.25f / 448.0f;
  #pragma unroll
  for (int i = 0; i < 4; ++i) {
    int c = c0 + ty + i * 8, p = p0 + tx;
    if (p < 3600) {
      size_t o = (size_t)c * 3600 + p;
      out[o] = 0.5f * fq[o] + wts * t[tx][ty + i * 8];
    }
  }
}

// ---------------------------------------------------------------------------
extern "C" void kernel_launch(void* const* d_in, const int* in_sizes, int n_in,
                              void* d_out, int out_size, void* d_ws, size_t ws_size,
                              hipStream_t stream) {
  const float* fq3 = (const float*)d_in[0];
  const float* fq4 = (const float*)d_in[1];
  const float* fs3 = (const float*)d_in[2];
  const float* fs4 = (const float*)d_in[3];
  const float* f_q = (const float*)d_in[4];
  const float* f_s = (const float*)d_in[5];
  const float* wch = (const float*)d_in[6];
  float* out = (float*)d_out;

  const size_t HW = 3600, MP = 3840, KC = 3072, CH = 512;

  // workspace (~94 MB)
  unsigned char* QT8 = (unsigned char*)d_ws;          // (KC/16, MP, 16B) fp8 query
  unsigned char* ST8 = QT8 + MP * KC;                 // (KC/16, MP, 16B) fp8 support
  unsigned char* V8  = ST8 + MP * KC;                 // (MP/16, CH, 16B) fp8 V
  unsigned short* Lb = (unsigned short*)(V8 + (MP / 16) * CH * 16);  // (MP,MP) bf16 logits
  unsigned char* Att8 = (unsigned char*)(Lb + MP * MP);  // (MP/16, MP, 16B) fp8 attn*448
  unsigned short* Pb = (unsigned short*)(Att8 + (MP / 16) * MP * 16); // 6 x (MP,CH) bf16
  float* invn = (float*)(Pb + 6 * MP * CH);           // 6 x 3600
  float* part = (float*)Lb;                           // norm scratch (consumed pre-GEMM)

  Src6 S;
  S.p[0] = fq4; S.p[1] = fs4; S.p[2] = fs4 + 2048 * HW;
  S.p[3] = fq3; S.p[4] = fs3; S.p[5] = fs3 + 1024 * HW;
  colnorm_part6_k<<<dim3(15, 16, 6), 256, 0, stream>>>(S, part);
  colnorm_fin6_k<<<dim3(4, 6), 256, 0, stream>>>(part, invn);

  dim3 tb(32, 8);
  tpose2_f8_k<<<dim3(113, 96), tb, 0, stream>>>(fq4, fq3, invn + 0 * HW, invn + 3 * HW,
                                                wch, 1, QT8);

  for (int b = 0; b < 2; ++b) {
    castv_f8_k<<<7200, 256, 0, stream>>>(f_s + (size_t)b * CH * HW, V8);
    tpose2_f8_k<<<dim3(113, 96), tb, 0, stream>>>(
        fs4 + (size_t)b * 2048 * HW, fs3 + (size_t)b * 1024 * HW,
        invn + (1 + b) * HW, invn + (4 + b) * HW, wch, 0, ST8);

    // logits (bf16) = QT8 . ST8^T (MX-fp8, unit scales); 30x30 = 900 blocks
    gemm128_f8<<<900, 256, 0, stream>>>(QT8, ST8, Lb, 3072, 3840, 3840, 30);

    softmax_rows_k<<<3600, 256, 0, stream>>>(Lb, Att8);

    // PV split-K=6, fp8 x fp8 -> bf16 partials (scale 448 folded in attn)
    pv_f8_k<<<dim3(30, 4, 6), 256, 0, stream>>>(Att8, V8, Pb, b);
  }

  final_blend_k<<<dim3(113, 16), tb, 0, stream>>>(Pb, f_q, out);
}

// Round 13
// 327.849 us; speedup vs baseline: 1.0185x; 1.0185x over previous
//
#include <hip/hip_runtime.h>
#include <cstdint>

#define TEMP_C 20.0f
#define FSCALE 16.0f   // fixed fp8 quantization scale for raw features

typedef float f32x4 __attribute__((ext_vector_type(4)));
typedef float f32x16 __attribute__((ext_vector_type(16)));
typedef int i32x4 __attribute__((ext_vector_type(4)));
typedef int i32x8 __attribute__((ext_vector_type(8)));

// fp32 -> bf16 round-to-nearest-even
__device__ __forceinline__ unsigned short f2bf(float f) {
  union { float f; unsigned int u; } v; v.f = f;
  unsigned int r = v.u + 0x7FFFu + ((v.u >> 16) & 1u);
  return (unsigned short)(r >> 16);
}
__device__ __forceinline__ float bf2f(unsigned short b) {
  union { unsigned int u; float f; } v; v.u = ((unsigned int)b) << 16;
  return v.f;
}

// fp32 -> OCP e4m3fn, RTNE, clamp to +-448
__device__ __forceinline__ unsigned char f2e4m3(float f) {
  unsigned u = __float_as_uint(f);
  unsigned s = (u >> 24) & 0x80u;
  float a = fminf(fabsf(f), 448.0f);
  if (a < 0.015625f) {
    int d = (int)rintf(a * 512.0f);
    return (unsigned char)(s | (unsigned)d);
  }
  unsigned au = __float_as_uint(a);
  unsigned r = au + 0xFFFFFu + ((au >> 20) & 1u);
  int Ep = (int)(r >> 23) - 127;
  if (Ep > 8) return (unsigned char)(s | 0x7E);
  unsigned m = (r >> 20) & 7u;
  return (unsigned char)(s | ((unsigned)(Ep + 7) << 3) | m);
}

// async global->LDS, 16B per lane (dest = wave-uniform base + lane*16)
__device__ __forceinline__ void gload_lds16(const void* g, void* l) {
  __builtin_amdgcn_global_load_lds(
      (__attribute__((address_space(1))) void*)(g),
      (__attribute__((address_space(3))) void*)(l), 16, 0, 0);
}

// ---------------------------------------------------------------------------
// 1) fused transpose + fixed-scale FP8 cast + per-(pixel, 32ch-group) sumsq
//    partials (norms now applied POST-GEMM in softmax — removes the separate
//    133MB colnorm pass). K-GROUP-MAJOR output: T[(g*3840+p)*16 + (col&15)].
//    part[y][p] = sum over this block's 32 channels of X[c][p]^2 (determin.).
__global__ __launch_bounds__(256) void tpose2_f8_k(
    const float* __restrict__ X4, const float* __restrict__ X3,
    unsigned char* __restrict__ T, float* __restrict__ part)
{
  __shared__ float tile[32][33];
  __shared__ float red2[8][33];
  const int tx = threadIdx.x, ty = threadIdx.y;
  const int y = blockIdx.y;
  const float* X; int c0, cdst;
  if (y < 64) { X = X4; c0 = y * 32;        cdst = c0; }
  else        { X = X3; c0 = (y - 64) * 32; cdst = 2048 + c0; }
  const int p0 = blockIdx.x * 32;
  #pragma unroll
  for (int i = 0; i < 4; ++i) {
    int c = c0 + ty + i * 8, p = p0 + tx;
    tile[ty + i * 8][tx] = (p < 3600) ? X[(size_t)c * 3600 + p] : 0.f;
  }
  __syncthreads();
  // sumsq partial: pixel tx, channels ty*4 .. ty*4+3 (zero-padded pixels -> 0)
  {
    float s = 0.f;
    #pragma unroll
    for (int k = 0; k < 4; ++k) { float v = tile[ty * 4 + k][tx]; s += v * v; }
    red2[ty][tx] = s;
  }
  // fp8 write (channel tx, pixel ty+8i), fixed scale
  const int col = cdst + tx;
  const size_t gbase = (size_t)(col >> 4) * 3840 * 16 + (col & 15);
  #pragma unroll
  for (int i = 0; i < 4; ++i) {
    int p = p0 + ty + i * 8;
    if (p < 3600) T[gbase + (size_t)p * 16] = f2e4m3(tile[tx][ty + i * 8] * FSCALE);
  }
  __syncthreads();
  if (ty == 0 && p0 + tx < 3600) {
    float s = 0.f;
    #pragma unroll
    for (int j = 0; j < 8; ++j) s += red2[j][tx];
    part[(size_t)y * 3600 + p0 + tx] = s;
  }
}

// 1b) finish: inv4[p] = 1/||x4_p||, inv3[p] = 1/||x3_p|| from 96 partials
__global__ __launch_bounds__(256) void norm_fin_k(
    const float* __restrict__ part, float* __restrict__ inv4,
    float* __restrict__ inv3)
{
  const int p = blockIdx.x * 256 + threadIdx.x;
  if (p >= 3600) return;
  float s4 = 0.f, s3 = 0.f;
  #pragma unroll
  for (int y = 0; y < 64; ++y) s4 += part[(size_t)y * 3600 + p];
  #pragma unroll
  for (int y = 64; y < 96; ++y) s3 += part[(size_t)y * 3600 + p];
  inv4[p] = 1.0f / fmaxf(sqrtf(s4), 1e-12f);
  inv3[p] = 1.0f / fmaxf(sqrtf(s3), 1e-12f);
}

// ---------------------------------------------------------------------------
// 2) V cast to fp8, K-group-major over s: V8[((s>>4)*512 + c)*16 + (s&15)]
__global__ void castv_f8_k(const float* __restrict__ X, unsigned char* __restrict__ V8)
{
  int i = blockIdx.x * 256 + threadIdx.x;
  if (i >= 512 * 3600) return;
  int c = i / 3600, s = i - c * 3600;
  V8[((size_t)(s >> 4) * 512 + c) * 16 + (s & 15)] = f2e4m3(X[i]);
}

// ---------------------------------------------------------------------------
// 3) 128x128 MX-fp8 GEMM — ROUND 11 VERIFIED STRUCTURE (both operands
//    LDS-staged via coalesced K-group-major chunks; 2 slots = 32KB;
//    counted vmcnt(4) depth-1 prefetch; 0 bank conflicts). Output bf16.
//    Launched twice per batch with A/B pre-offset to the level's k-groups.
__global__ __launch_bounds__(256, 4) void gemm128_f8(
    const unsigned char* __restrict__ A, const unsigned char* __restrict__ B,
    unsigned short* __restrict__ C, int K, int MPr, int ldc, int nbn)
{
  __shared__ __align__(16) unsigned char As[2][8192];   // [4 g][128 rows][16B]
  __shared__ __align__(16) unsigned char Bs[2][8192];

  const int tid  = threadIdx.x;
  const int lane = tid & 63;
  const int wave = tid >> 6;     // 0..3
  const int wrow = wave >> 1;    // 0..1 (M half)
  const int wcol = wave & 1;     // 0..1 (N half)

  // XCD-aware bijective block remap (m204)
  const int nwg = gridDim.x;
  const int q8 = nwg >> 3, r8 = nwg & 7;
  const int xcd = blockIdx.x & 7, bidx = blockIdx.x >> 3;
  const int wg = (xcd < r8 ? xcd * (q8 + 1) : r8 * (q8 + 1) + (xcd - r8) * q8) + bidx;
  const long Arow0 = (long)(wg / nbn) * 128;
  const long Brow0 = (long)(wg % nbn) * 128;

  const unsigned char* sA[2];
  const unsigned char* sB[2];
  #pragma unroll
  for (int q = 0; q < 2; ++q) {
    const int c = q * 256 + tid;
    const int g = c >> 7, r = c & 127;
    sA[q] = A + ((long)g * MPr + Arow0 + r) * 16;
    sB[q] = B + ((long)g * MPr + Brow0 + r) * 16;
  }
  const long kstride = (long)MPr * 16 * 4;   // 4 groups per K-tile (BK=64)

  #define STAGE(tt) do { const int _sl = (tt) & 1; const long _ko = (long)(tt) * kstride; \
    gload_lds16(sA[0] + _ko, &As[_sl][tid * 16]);              \
    gload_lds16(sA[1] + _ko, &As[_sl][(256 + tid) * 16]);      \
    gload_lds16(sB[0] + _ko, &Bs[_sl][tid * 16]);              \
    gload_lds16(sB[1] + _ko, &Bs[_sl][(256 + tid) * 16]);      \
  } while (0)

  const int l31 = lane & 31, lk = lane >> 5;
  const int arow0 = (wrow * 64 + l31) * 16;   // m-tile 0; m=1 at +512
  const int brow0 = (wcol * 64 + l31) * 16;

  f32x16 acc[2][2] = {};
  const int NT = K >> 6;

  STAGE(0);

  for (int t = 0; t < NT; ++t) {
    const int sl = t & 1;
    if (t + 1 < NT) {
      STAGE(t + 1);
      asm volatile("s_waitcnt vmcnt(4)" ::: "memory");  // tile t landed; t+1 in flight
    } else {
      asm volatile("s_waitcnt vmcnt(0)" ::: "memory");
    }
    asm volatile("s_barrier" ::: "memory");             // slot sl visible to all waves

    const unsigned char* Ap = As[sl];
    const unsigned char* Bp = Bs[sl];
    #define LDF(base, rowb, s) (*(const i32x4*)((base) + (((lk * 2 + (s)) << 11) + (rowb))))
    #define FRAG(dst, base, rowb) do {                  \
      i32x4 _lo = LDF(base, rowb, 0);                   \
      i32x4 _hi = LDF(base, rowb, 1);                   \
      dst[0]=_lo[0]; dst[1]=_lo[1]; dst[2]=_lo[2]; dst[3]=_lo[3]; \
      dst[4]=_hi[0]; dst[5]=_hi[1]; dst[6]=_hi[2]; dst[7]=_hi[3]; \
    } while (0)
    #define MFMA8(a, b, m, n) \
      acc[m][n] = __builtin_amdgcn_mfma_scale_f32_32x32x64_f8f6f4( \
          a, b, acc[m][n], 0, 0, 0, 127, 0, 127)

    i32x8 a0, a1, b0, b1;
    FRAG(a0, Ap, arow0); FRAG(a1, Ap, arow0 + 512);
    FRAG(b0, Bp, brow0); FRAG(b1, Bp, brow0 + 512);
    __builtin_amdgcn_s_setprio(1);
    MFMA8(a0, b0, 0, 0); MFMA8(a0, b1, 0, 1);
    MFMA8(a1, b0, 1, 0); MFMA8(a1, b1, 1, 1);
    __builtin_amdgcn_s_setprio(0);
    #undef LDF
    #undef FRAG
    #undef MFMA8
    asm volatile("s_barrier" ::: "memory");             // all reads of slot sl done
  }
  #undef STAGE

  // epilogue (bf16): col=lane&31, row = (reg&3) + 8*(reg>>2) + 4*(lane>>5)
  #pragma unroll
  for (int m = 0; m < 2; ++m) {
    const long rowb = Arow0 + wrow * 64 + m * 32;
    #pragma unroll
    for (int g4 = 0; g4 < 4; ++g4) {
      #pragma unroll
      for (int r4 = 0; r4 < 4; ++r4) {
        const long row = rowb + r4 + 8 * g4 + 4 * lk;
        unsigned short* cp = C + row * (long)ldc + Brow0 + wcol * 64 + l31;
        cp[0]  = f2bf(acc[m][0][g4 * 4 + r4]);
        cp[32] = f2bf(acc[m][1][g4 * 4 + r4]);
      }
    }
  }
}

// ---------------------------------------------------------------------------
// 4) PV MX-fp8 GEMM (round 10, verified): P[z][q][c] (+)= Att8[q][s]*V8[c][s].
__global__ __launch_bounds__(256, 2) void pv_f8_k(
    const unsigned char* __restrict__ Att, const unsigned char* __restrict__ V,
    unsigned short* __restrict__ P, int accumulate)
{
  __shared__ __align__(16) unsigned char As[2][128 * 128];
  __shared__ __align__(16) unsigned char Bs[2][128 * 128];

  const int tid  = threadIdx.x;
  const int lane = tid & 63;
  const int wave = tid >> 6;
  const int wrow = wave >> 1;
  const int wcol = wave & 1;
  const long Arow0 = (long)blockIdx.x * 128;   // q
  const long Brow0 = (long)blockIdx.y * 128;   // c
  const int z = blockIdx.z;
  P += (long)z * 3840 * 512;

  const unsigned char* sA[4];
  const unsigned char* sB[4];
  #pragma unroll
  for (int q = 0; q < 4; ++q) {
    const int c = q * 256 + tid;
    const int g = c >> 7, r = c & 127;
    sA[q] = Att + ((long)(z * 40 + g) * 3840 + Arow0 + r) * 16;
    sB[q] = V   + ((long)(z * 40 + g) * 512  + Brow0 + r) * 16;
  }
  const long ksA = 3840L * 16 * 8;
  const long ksB = 512L * 16 * 8;

  #define STAGE(tt) do { const int _sl = (tt) & 1;                          \
    _Pragma("unroll")                                                       \
    for (int q = 0; q < 4; ++q)                                             \
      gload_lds16(sA[q] + (long)(tt) * ksA, &As[_sl][(q * 256 + tid) * 16]);\
    _Pragma("unroll")                                                       \
    for (int q = 0; q < 4; ++q)                                             \
      gload_lds16(sB[q] + (long)(tt) * ksB, &Bs[_sl][(q * 256 + tid) * 16]);\
  } while (0)

  const int l31 = lane & 31, lk = lane >> 5;
  const int arow0 = (wrow * 64 + l31) * 16;
  const int brow0 = (wcol * 64 + l31) * 16;

  f32x16 acc[2][2] = {};
  const int NT = 5;

  STAGE(0);

  for (int t = 0; t < NT; ++t) {
    const int sl = t & 1;
    if (t + 1 < NT) {
      STAGE(t + 1);
      asm volatile("s_waitcnt vmcnt(8)" ::: "memory");
    } else {
      asm volatile("s_waitcnt vmcnt(0)" ::: "memory");
    }
    asm volatile("s_barrier" ::: "memory");

    const unsigned char* Ap = As[sl];
    const unsigned char* Bp = Bs[sl];
    #define LDF(base, rowb, h, s) \
      (*(const i32x4*)((base) + ((((h) * 4 + lk * 2 + (s)) << 11) + (rowb))))
    #define FRAG(dst, base, rowb, h) do {               \
      i32x4 _lo = LDF(base, rowb, h, 0);                \
      i32x4 _hi = LDF(base, rowb, h, 1);                \
      dst[0]=_lo[0]; dst[1]=_lo[1]; dst[2]=_lo[2]; dst[3]=_lo[3]; \
      dst[4]=_hi[0]; dst[5]=_hi[1]; dst[6]=_hi[2]; dst[7]=_hi[3]; \
    } while (0)
    #define MFMA8(a, b, m, n) \
      acc[m][n] = __builtin_amdgcn_mfma_scale_f32_32x32x64_f8f6f4( \
          a, b, acc[m][n], 0, 0, 0, 127, 0, 127)

    #pragma unroll
    for (int h = 0; h < 2; ++h) {
      i32x8 a0, a1, b0, b1;
      FRAG(a0, Ap, arow0, h); FRAG(a1, Ap, arow0 + 512, h);
      FRAG(b0, Bp, brow0, h); FRAG(b1, Bp, brow0 + 512, h);
      __builtin_amdgcn_s_setprio(1);
      MFMA8(a0, b0, 0, 0); MFMA8(a0, b1, 0, 1);
      MFMA8(a1, b0, 1, 0); MFMA8(a1, b1, 1, 1);
      __builtin_amdgcn_s_setprio(0);
    }
    #undef LDF
    #undef FRAG
    #undef MFMA8
    asm volatile("s_barrier" ::: "memory");
  }
  #undef STAGE

  #pragma unroll
  for (int m = 0; m < 2; ++m) {
    const long rowb = Arow0 + wrow * 64 + m * 32;
    #pragma unroll
    for (int g4 = 0; g4 < 4; ++g4) {
      #pragma unroll
      for (int r4 = 0; r4 < 4; ++r4) {
        const long row = rowb + r4 + 8 * g4 + 4 * lk;
        unsigned short* cp = P + row * 512 + Brow0 + wcol * 64 + l31;
        float v0 = acc[m][0][g4 * 4 + r4];
        float v1 = acc[m][1][g4 * 4 + r4];
        if (accumulate) { v0 += bf2f(cp[0]); v1 += bf2f(cp[32]); }
        cp[0]  = f2bf(v0);
        cp[32] = f2bf(v1);
      }
    }
  }
}

// ---------------------------------------------------------------------------
// 5) row softmax with POST-GEMM norm application:
//    logit[s] = (TEMP*w0/FS^2)*L4[q][s]*invq4[q]*invs4[s]
//             + (TEMP*w1/FS^2)*L3[q][s]*invq3[q]*invs3[s]
//    then softmax over s<3600, write fp8 attn*448 K-group-major.
__global__ __launch_bounds__(256) void softmax_rows_k(
    const unsigned short* __restrict__ L4, const unsigned short* __restrict__ L3,
    const float* __restrict__ invq4, const float* __restrict__ invq3,
    const float* __restrict__ invs4, const float* __restrict__ invs3,
    const float* __restrict__ wch, unsigned char* __restrict__ Att)
{
  const int q = blockIdx.x;
  const unsigned short* r4 = L4 + (size_t)q * 3840;
  const unsigned short* r3 = L3 + (size_t)q * 3840;
  const float c4 = (TEMP_C / (FSCALE * FSCALE)) * wch[0] * invq4[q];
  const float c3 = (TEMP_C / (FSCALE * FSCALE)) * wch[1] * invq3[q];
  const int tid = threadIdx.x;
  float v[15];
  float mx = -1e30f;
  #pragma unroll
  for (int j = 0; j < 15; ++j) {
    int s = tid + j * 256;
    float x = -1e30f;
    if (s < 3600)
      x = c4 * bf2f(r4[s]) * invs4[s] + c3 * bf2f(r3[s]) * invs3[s];
    v[j] = x;
    mx = fmaxf(mx, x);
  }
  #pragma unroll
  for (int o = 32; o > 0; o >>= 1) mx = fmaxf(mx, __shfl_xor(mx, o));
  __shared__ float wmax[4], wsum[4];
  if ((tid & 63) == 0) wmax[tid >> 6] = mx;
  __syncthreads();
  mx = fmaxf(fmaxf(wmax[0], wmax[1]), fmaxf(wmax[2], wmax[3]));
  float sum = 0.f;
  #pragma unroll
  for (int j = 0; j < 15; ++j) {
    int s = tid + j * 256;
    float e = (s < 3600) ? __expf(v[j] - mx) : 0.f;
    v[j] = e;
    sum += e;
  }
  #pragma unroll
  for (int o = 32; o > 0; o >>= 1) sum += __shfl_xor(sum, o);
  if ((tid & 63) == 0) wsum[tid >> 6] = sum;
  __syncthreads();
  sum = wsum[0] + wsum[1] + wsum[2] + wsum[3];
  const float inv448 = 448.0f / sum;
  #pragma unroll
  for (int j = 0; j < 15; ++j) {
    int s = tid + j * 256;
    unsigned char b = (s < 3600) ? f2e4m3(v[j] * inv448) : (unsigned char)0;
    Att[((size_t)(s >> 4) * 3840 + q) * 16 + (s & 15)] = b;
  }
}

// ---------------------------------------------------------------------------
// 6) out[c][p] = 0.5*f_q[c][p] + (0.25/448)*sum_z P[z][p][c]  (bf16 partials)
__global__ __launch_bounds__(256) void final_blend_k(
    const unsigned short* __restrict__ P, const float* __restrict__ fq,
    float* __restrict__ out)
{
  __shared__ float t[32][33];
  const int tx = threadIdx.x, ty = threadIdx.y;
  const int p0 = blockIdx.x * 32, c0 = blockIdx.y * 32;
  const long ZC = 3840L * 512;
  #pragma unroll
  for (int i = 0; i < 4; ++i) {
    int p = p0 + ty + i * 8, c = c0 + tx;
    float s = 0.f;
    if (p < 3600) {
      size_t o = (size_t)p * 512 + c;
      #pragma unroll
      for (int z = 0; z < 6; ++z) s += bf2f(P[o + (size_t)z * ZC]);
    }
    t[ty + i * 8][tx] = s;
  }
  __syncthreads();
  const float wts = 0.25f / 448.0f;
  #pragma unroll
  for (int i = 0; i < 4; ++i) {
    int c = c0 + ty + i * 8, p = p0 + tx;
    if (p < 3600) {
      size_t o = (size_t)c * 3600 + p;
      out[o] = 0.5f * fq[o] + wts * t[tx][ty + i * 8];
    }
  }
}

// ---------------------------------------------------------------------------
extern "C" void kernel_launch(void* const* d_in, const int* in_sizes, int n_in,
                              void* d_out, int out_size, void* d_ws, size_t ws_size,
                              hipStream_t stream) {
  const float* fq3 = (const float*)d_in[0];
  const float* fq4 = (const float*)d_in[1];
  const float* fs3 = (const float*)d_in[2];
  const float* fs4 = (const float*)d_in[3];
  const float* f_q = (const float*)d_in[4];
  const float* f_s = (const float*)d_in[5];
  const float* wch = (const float*)d_in[6];
  float* out = (float*)d_out;

  const size_t HW = 3600, MP = 3840, KC = 3072, CH = 512;

  // workspace (~126 MB)
  unsigned char* QT8 = (unsigned char*)d_ws;          // (KC/16, MP, 16B) fp8 query (raw*16)
  unsigned char* ST8 = QT8 + MP * KC;                 // (KC/16, MP, 16B) fp8 support
  unsigned char* V8  = ST8 + MP * KC;                 // (MP/16, CH, 16B) fp8 V
  unsigned short* L4 = (unsigned short*)(V8 + MP * CH);   // (MP,MP) bf16 level-4 dots
  unsigned short* L3 = L4 + MP * MP;                  // (MP,MP) bf16 level-3 dots
  unsigned char* Att8 = (unsigned char*)(L3 + MP * MP);   // (MP/16, MP, 16B) fp8 attn*448
  unsigned short* Pb = (unsigned short*)(Att8 + MP * MP); // 6 x (MP,CH) bf16 partials
  float* invq4 = (float*)(Pb + 6 * MP * CH);          // 4 x 3600 norm inverses
  float* invq3 = invq4 + HW;
  float* invs4 = invq3 + HW;
  float* invs3 = invs4 + HW;
  float* partQ = invs3 + HW;                          // 96 x 3600
  float* partS = partQ + 96 * HW;                     // 96 x 3600

  dim3 tb(32, 8);
  // query side: fp8 (fixed scale) + norm partials, once
  tpose2_f8_k<<<dim3(113, 96), tb, 0, stream>>>(fq4, fq3, QT8, partQ);
  norm_fin_k<<<15, 256, 0, stream>>>(partQ, invq4, invq3);

  const long G4OFF = 128L * MP * 16;   // byte offset of k-group 128 (level-3 cols)

  for (int b = 0; b < 2; ++b) {
    castv_f8_k<<<7200, 256, 0, stream>>>(f_s + (size_t)b * CH * HW, V8);
    tpose2_f8_k<<<dim3(113, 96), tb, 0, stream>>>(
        fs4 + (size_t)b * 2048 * HW, fs3 + (size_t)b * 1024 * HW, ST8, partS);
    norm_fin_k<<<15, 256, 0, stream>>>(partS, invs4, invs3);

    // raw dot products per level (bf16): L4 = Q4.S4^T (K=2048), L3 = Q3.S3^T (K=1024)
    gemm128_f8<<<900, 256, 0, stream>>>(QT8, ST8, L4, 2048, 3840, 3840, 30);
    gemm128_f8<<<900, 256, 0, stream>>>(QT8 + G4OFF, ST8 + G4OFF, L3, 1024, 3840, 3840, 30);

    // softmax with post-GEMM norm/weight application -> fp8 attn
    softmax_rows_k<<<3600, 256, 0, stream>>>(L4, L3, invq4, invq3, invs4, invs3,
                                             wch, Att8);

    // PV split-K=6, fp8 x fp8 -> bf16 partials (scale 448 folded in attn)
    pv_f8_k<<<dim3(30, 4, 6), 256, 0, stream>>>(Att8, V8, Pb, b);
  }

  final_blend_k<<<dim3(113, 16), tb, 0, stream>>>(Pb, f_q, out);
}

// Round 14
// 293.279 us; speedup vs baseline: 1.1386x; 1.1179x over previous
//
#include <hip/hip_runtime.h>
#include <cstdint>

#define TEMP_C 20.0f
#define FSCALE 16.0f   // fixed fp8 quantization scale for raw features

typedef float f32x4 __attribute__((ext_vector_type(4)));
typedef float f32x16 __attribute__((ext_vector_type(16)));
typedef int i32x4 __attribute__((ext_vector_type(4)));
typedef int i32x8 __attribute__((ext_vector_type(8)));

// fp32 -> bf16 round-to-nearest-even
__device__ __forceinline__ unsigned short f2bf(float f) {
  union { float f; unsigned int u; } v; v.f = f;
  unsigned int r = v.u + 0x7FFFu + ((v.u >> 16) & 1u);
  return (unsigned short)(r >> 16);
}
__device__ __forceinline__ float bf2f(unsigned short b) {
  union { unsigned int u; float f; } v; v.u = ((unsigned int)b) << 16;
  return v.f;
}

// fp32 -> OCP e4m3fn, RTNE, clamp to +-448
__device__ __forceinline__ unsigned char f2e4m3(float f) {
  unsigned u = __float_as_uint(f);
  unsigned s = (u >> 24) & 0x80u;
  float a = fminf(fabsf(f), 448.0f);
  if (a < 0.015625f) {
    int d = (int)rintf(a * 512.0f);
    return (unsigned char)(s | (unsigned)d);
  }
  unsigned au = __float_as_uint(a);
  unsigned r = au + 0xFFFFFu + ((au >> 20) & 1u);
  int Ep = (int)(r >> 23) - 127;
  if (Ep > 8) return (unsigned char)(s | 0x7E);
  unsigned m = (r >> 20) & 7u;
  return (unsigned char)(s | ((unsigned)(Ep + 7) << 3) | m);
}

// async global->LDS, 16B per lane (dest = wave-uniform base + lane*16)
__device__ __forceinline__ void gload_lds16(const void* g, void* l) {
  __builtin_amdgcn_global_load_lds(
      (__attribute__((address_space(1))) void*)(g),
      (__attribute__((address_space(3))) void*)(l), 16, 0, 0);
}

// ---------------------------------------------------------------------------
// 1) fused transpose + fixed-scale FP8 cast + per-(pixel, 32ch-group) sumsq
//    partials (norms applied POST-GEMM in softmax). K-GROUP-MAJOR output.
__global__ __launch_bounds__(256) void tpose2_f8_k(
    const float* __restrict__ X4, const float* __restrict__ X3,
    unsigned char* __restrict__ T, float* __restrict__ part)
{
  __shared__ float tile[32][33];
  __shared__ float red2[8][33];
  const int tx = threadIdx.x, ty = threadIdx.y;
  const int y = blockIdx.y;
  const float* X; int c0, cdst;
  if (y < 64) { X = X4; c0 = y * 32;        cdst = c0; }
  else        { X = X3; c0 = (y - 64) * 32; cdst = 2048 + c0; }
  const int p0 = blockIdx.x * 32;
  #pragma unroll
  for (int i = 0; i < 4; ++i) {
    int c = c0 + ty + i * 8, p = p0 + tx;
    tile[ty + i * 8][tx] = (p < 3600) ? X[(size_t)c * 3600 + p] : 0.f;
  }
  __syncthreads();
  {
    float s = 0.f;
    #pragma unroll
    for (int k = 0; k < 4; ++k) { float v = tile[ty * 4 + k][tx]; s += v * v; }
    red2[ty][tx] = s;
  }
  const int col = cdst + tx;
  const size_t gbase = (size_t)(col >> 4) * 3840 * 16 + (col & 15);
  #pragma unroll
  for (int i = 0; i < 4; ++i) {
    int p = p0 + ty + i * 8;
    if (p < 3600) T[gbase + (size_t)p * 16] = f2e4m3(tile[tx][ty + i * 8] * FSCALE);
  }
  __syncthreads();
  if (ty == 0 && p0 + tx < 3600) {
    float s = 0.f;
    #pragma unroll
    for (int j = 0; j < 8; ++j) s += red2[j][tx];
    part[(size_t)y * 3600 + p0 + tx] = s;
  }
}

// 1b) finish: inv4[p] = 1/||x4_p||, inv3[p] = 1/||x3_p|| from 96 partials
__global__ __launch_bounds__(256) void norm_fin_k(
    const float* __restrict__ part, float* __restrict__ inv4,
    float* __restrict__ inv3)
{
  const int p = blockIdx.x * 256 + threadIdx.x;
  if (p >= 3600) return;
  float s4 = 0.f, s3 = 0.f;
  #pragma unroll
  for (int y = 0; y < 64; ++y) s4 += part[(size_t)y * 3600 + p];
  #pragma unroll
  for (int y = 64; y < 96; ++y) s3 += part[(size_t)y * 3600 + p];
  inv4[p] = 1.0f / fmaxf(sqrtf(s4), 1e-12f);
  inv3[p] = 1.0f / fmaxf(sqrtf(s3), 1e-12f);
}

// ---------------------------------------------------------------------------
// 2) V cast to fp8, K-group-major over s: V8[((s>>4)*512 + c)*16 + (s&15)]
__global__ void castv_f8_k(const float* __restrict__ X, unsigned char* __restrict__ V8)
{
  int i = blockIdx.x * 256 + threadIdx.x;
  if (i >= 512 * 3600) return;
  int c = i / 3600, s = i - c * 3600;
  V8[((size_t)(s >> 4) * 512 + c) * 16 + (s & 15)] = f2e4m3(X[i]);
}

// ---------------------------------------------------------------------------
// 3) 128x128 MX-fp8 GEMM — ROUND 11 VERIFIED STRUCTURE (unchanged).
__global__ __launch_bounds__(256, 4) void gemm128_f8(
    const unsigned char* __restrict__ A, const unsigned char* __restrict__ B,
    unsigned short* __restrict__ C, int K, int MPr, int ldc, int nbn)
{
  __shared__ __align__(16) unsigned char As[2][8192];
  __shared__ __align__(16) unsigned char Bs[2][8192];

  const int tid  = threadIdx.x;
  const int lane = tid & 63;
  const int wave = tid >> 6;
  const int wrow = wave >> 1;
  const int wcol = wave & 1;

  const int nwg = gridDim.x;
  const int q8 = nwg >> 3, r8 = nwg & 7;
  const int xcd = blockIdx.x & 7, bidx = blockIdx.x >> 3;
  const int wg = (xcd < r8 ? xcd * (q8 + 1) : r8 * (q8 + 1) + (xcd - r8) * q8) + bidx;
  const long Arow0 = (long)(wg / nbn) * 128;
  const long Brow0 = (long)(wg % nbn) * 128;

  const unsigned char* sA[2];
  const unsigned char* sB[2];
  #pragma unroll
  for (int q = 0; q < 2; ++q) {
    const int c = q * 256 + tid;
    const int g = c >> 7, r = c & 127;
    sA[q] = A + ((long)g * MPr + Arow0 + r) * 16;
    sB[q] = B + ((long)g * MPr + Brow0 + r) * 16;
  }
  const long kstride = (long)MPr * 16 * 4;

  #define STAGE(tt) do { const int _sl = (tt) & 1; const long _ko = (long)(tt) * kstride; \
    gload_lds16(sA[0] + _ko, &As[_sl][tid * 16]);              \
    gload_lds16(sA[1] + _ko, &As[_sl][(256 + tid) * 16]);      \
    gload_lds16(sB[0] + _ko, &Bs[_sl][tid * 16]);              \
    gload_lds16(sB[1] + _ko, &Bs[_sl][(256 + tid) * 16]);      \
  } while (0)

  const int l31 = lane & 31, lk = lane >> 5;
  const int arow0 = (wrow * 64 + l31) * 16;
  const int brow0 = (wcol * 64 + l31) * 16;

  f32x16 acc[2][2] = {};
  const int NT = K >> 6;

  STAGE(0);

  for (int t = 0; t < NT; ++t) {
    const int sl = t & 1;
    if (t + 1 < NT) {
      STAGE(t + 1);
      asm volatile("s_waitcnt vmcnt(4)" ::: "memory");
    } else {
      asm volatile("s_waitcnt vmcnt(0)" ::: "memory");
    }
    asm volatile("s_barrier" ::: "memory");

    const unsigned char* Ap = As[sl];
    const unsigned char* Bp = Bs[sl];
    #define LDF(base, rowb, s) (*(const i32x4*)((base) + (((lk * 2 + (s)) << 11) + (rowb))))
    #define FRAG(dst, base, rowb) do {                  \
      i32x4 _lo = LDF(base, rowb, 0);                   \
      i32x4 _hi = LDF(base, rowb, 1);                   \
      dst[0]=_lo[0]; dst[1]=_lo[1]; dst[2]=_lo[2]; dst[3]=_lo[3]; \
      dst[4]=_hi[0]; dst[5]=_hi[1]; dst[6]=_hi[2]; dst[7]=_hi[3]; \
    } while (0)
    #define MFMA8(a, b, m, n) \
      acc[m][n] = __builtin_amdgcn_mfma_scale_f32_32x32x64_f8f6f4( \
          a, b, acc[m][n], 0, 0, 0, 127, 0, 127)

    i32x8 a0, a1, b0, b1;
    FRAG(a0, Ap, arow0); FRAG(a1, Ap, arow0 + 512);
    FRAG(b0, Bp, brow0); FRAG(b1, Bp, brow0 + 512);
    __builtin_amdgcn_s_setprio(1);
    MFMA8(a0, b0, 0, 0); MFMA8(a0, b1, 0, 1);
    MFMA8(a1, b0, 1, 0); MFMA8(a1, b1, 1, 1);
    __builtin_amdgcn_s_setprio(0);
    #undef LDF
    #undef FRAG
    #undef MFMA8
    asm volatile("s_barrier" ::: "memory");
  }
  #undef STAGE

  #pragma unroll
  for (int m = 0; m < 2; ++m) {
    const long rowb = Arow0 + wrow * 64 + m * 32;
    #pragma unroll
    for (int g4 = 0; g4 < 4; ++g4) {
      #pragma unroll
      for (int r4 = 0; r4 < 4; ++r4) {
        const long row = rowb + r4 + 8 * g4 + 4 * lk;
        unsigned short* cp = C + row * (long)ldc + Brow0 + wcol * 64 + l31;
        cp[0]  = f2bf(acc[m][0][g4 * 4 + r4]);
        cp[32] = f2bf(acc[m][1][g4 * 4 + r4]);
      }
    }
  }
}

// ---------------------------------------------------------------------------
// 4) PV MX-fp8 GEMM, deep-pipelined: P[z][q][c] (+)= Att8[q][s]*V8[c][s].
//    BK=64 (4 groups), 4 LDS slots (64KB, 2 blocks/CU), split-K z=3 ->
//    20 tiles/block, prefetch depth 3 (vmcnt(8) waits loads issued 3 tiles
//    ~900cyc earlier), ONE barrier/tile (stage-after-barrier: slot (t+3)&3 =
//    (t-1)&3 whose reads all waves retired via lgkmcnt(0) before this BAR).
//    Grid: linear 360 (360%8==0), m204-chunked; (y,z) innermost so each
//    XCD's contiguous range covers all 12 (y,z) blocks of an x -> Att q-panel
//    fetched ~once per XCD (cuts the 4x refetch seen in r13).
__global__ __launch_bounds__(256, 2) void pv_f8_k(
    const unsigned char* __restrict__ Att, const unsigned char* __restrict__ V,
    unsigned short* __restrict__ P, int accumulate)
{
  __shared__ __align__(16) unsigned char As[4][4096];   // [4 g][64..] A: 128q x 64s = 8KB? -> per slot 8KB
  __shared__ __align__(16) unsigned char As2[4][4096];
  __shared__ __align__(16) unsigned char Bs[4][4096];
  __shared__ __align__(16) unsigned char Bs2[4][4096];
  // (A slot = As[sl] ++ As2[sl] logically; chunks 0..255 in As, 256..511 in As2)

  const int tid  = threadIdx.x;
  const int lane = tid & 63;
  const int wave = tid >> 6;
  const int wrow = wave >> 1;    // 0..1 (q half)
  const int wcol = wave & 1;     // 0..1 (c half)

  // chunked XCD decode: nwg=360 -> q8=45, r8=0
  const int xcd = blockIdx.x & 7, bidx = blockIdx.x >> 3;
  const int wg = xcd * 45 + bidx;
  const int x = wg / 12, rem = wg % 12;
  const int y = rem & 3, z = rem >> 2;     // z in 0..2
  const long Arow0 = (long)x * 128;        // q
  const long Brow0 = (long)y * 128;        // c
  P += (long)z * 3840 * 512;

  // staging: per tile 512 chunks of 16B per operand? A: 128q x 4g = 512 chunks/8KB
  // thread owns A chunks c = tid (g=tid>>7? no: 4 groups x 128 rows = 512) ...
  // chunk c: g = c >> 7 (0..3), r = c & 127. threads cover c = tid, 256+tid.
  const unsigned char* sA[2];
  const unsigned char* sB[2];
  #pragma unroll
  for (int q = 0; q < 2; ++q) {
    const int c = q * 256 + tid;
    const int g = c >> 7, r = c & 127;
    sA[q] = Att + ((long)(z * 80 + g) * 3840 + Arow0 + r) * 16;
    sB[q] = V   + ((long)(z * 80 + g) * 512  + Brow0 + r) * 16;
  }
  const long ksA = 3840L * 16 * 4;   // 4 groups per K-tile
  const long ksB = 512L * 16 * 4;

  // LDS dest: chunk c<256 -> As[sl][c*16]; c>=256 -> As2[sl][(c-256)*16]
  #define STAGE(tt) do { const int _sl = (tt) & 3;                      \
    gload_lds16(sA[0] + (long)(tt) * ksA, &As[_sl][tid * 16]);          \
    gload_lds16(sA[1] + (long)(tt) * ksA, &As2[_sl][tid * 16]);         \
    gload_lds16(sB[0] + (long)(tt) * ksB, &Bs[_sl][tid * 16]);          \
    gload_lds16(sB[1] + (long)(tt) * ksB, &Bs2[_sl][tid * 16]);         \
  } while (0)

  const int l31 = lane & 31, lk = lane >> 5;
  // fragment read: group gg = lk*2+s (0..3), row r -> chunk gg*128+r.
  // chunk < 256 (gg<2) in As/Bs, else As2/Bs2 at (gg-2)*128+r.
  const int arow0 = (wrow * 64 + l31) * 16;   // m=0; m=1 at +512 (32 rows)
  const int brow0 = (wcol * 64 + l31) * 16;

  f32x16 acc[2][2] = {};
  const int NT = 20;

  STAGE(0); STAGE(1); STAGE(2);

  for (int t = 0; t < NT; ++t) {
    const int sl = t & 3;
    const int rem_t = NT - 1 - t;
    if (rem_t >= 2)      asm volatile("s_waitcnt vmcnt(8)" ::: "memory");
    else if (rem_t == 1) asm volatile("s_waitcnt vmcnt(4)" ::: "memory");
    else                 asm volatile("s_waitcnt vmcnt(0)" ::: "memory");
    asm volatile("s_barrier" ::: "memory");   // slot sl complete for all waves;
                                              // also fences reads of slot (t-1)&3
    if (t + 3 < NT) STAGE(t + 3);             // -> slot (t+3)&3 == (t-1)&3

    // frag reads: lane groups lk*2 (in *s) and lk*2+1 (in *s too: gg=0,1 in As/Bs;
    // lk=1 -> gg=2,3 in As2/Bs2). group stride within a buffer = 2048B.
    const unsigned char* ApL = lk ? As2[sl] : As[sl];
    const unsigned char* BpL = lk ? Bs2[sl] : Bs[sl];
    #define LDF(base, rowb, s) (*(const i32x4*)((base) + (((s) << 11) + (rowb))))
    #define FRAG(dst, base, rowb) do {                  \
      i32x4 _lo = LDF(base, rowb, 0);                   \
      i32x4 _hi = LDF(base, rowb, 1);                   \
      dst[0]=_lo[0]; dst[1]=_lo[1]; dst[2]=_lo[2]; dst[3]=_lo[3]; \
      dst[4]=_hi[0]; dst[5]=_hi[1]; dst[6]=_hi[2]; dst[7]=_hi[3]; \
    } while (0)
    #define MFMA8(a, b, m, n) \
      acc[m][n] = __builtin_amdgcn_mfma_scale_f32_32x32x64_f8f6f4( \
          a, b, acc[m][n], 0, 0, 0, 127, 0, 127)

    i32x8 a0, a1, b0, b1;
    FRAG(a0, ApL, arow0); FRAG(a1, ApL, arow0 + 512);
    FRAG(b0, BpL, brow0); FRAG(b1, BpL, brow0 + 512);
    asm volatile("s_waitcnt lgkmcnt(0)" ::: "memory");
    __builtin_amdgcn_sched_barrier(0);
    __builtin_amdgcn_s_setprio(1);
    MFMA8(a0, b0, 0, 0); MFMA8(a0, b1, 0, 1);
    MFMA8(a1, b0, 1, 0); MFMA8(a1, b1, 1, 1);
    __builtin_amdgcn_s_setprio(0);
    #undef LDF
    #undef FRAG
    #undef MFMA8
  }
  #undef STAGE

  // epilogue: col=lane&31, row=(reg&3)+8*(reg>>2)+4*(lane>>5); bf16 RMW
  #pragma unroll
  for (int m = 0; m < 2; ++m) {
    const long rowb = Arow0 + wrow * 64 + m * 32;
    #pragma unroll
    for (int g4 = 0; g4 < 4; ++g4) {
      #pragma unroll
      for (int r4 = 0; r4 < 4; ++r4) {
        const long row = rowb + r4 + 8 * g4 + 4 * lk;
        unsigned short* cp = P + row * 512 + Brow0 + wcol * 64 + l31;
        float v0 = acc[m][0][g4 * 4 + r4];
        float v1 = acc[m][1][g4 * 4 + r4];
        if (accumulate) { v0 += bf2f(cp[0]); v1 += bf2f(cp[32]); }
        cp[0]  = f2bf(v0);
        cp[32] = f2bf(v1);
      }
    }
  }
}

// ---------------------------------------------------------------------------
// 5) row softmax with POST-GEMM norm application -> fp8 attn*448, K-group-major
__global__ __launch_bounds__(256) void softmax_rows_k(
    const unsigned short* __restrict__ L4, const unsigned short* __restrict__ L3,
    const float* __restrict__ invq4, const float* __restrict__ invq3,
    const float* __restrict__ invs4, const float* __restrict__ invs3,
    const float* __restrict__ wch, unsigned char* __restrict__ Att)
{
  const int q = blockIdx.x;
  const unsigned short* r4 = L4 + (size_t)q * 3840;
  const unsigned short* r3 = L3 + (size_t)q * 3840;
  const float c4 = (TEMP_C / (FSCALE * FSCALE)) * wch[0] * invq4[q];
  const float c3 = (TEMP_C / (FSCALE * FSCALE)) * wch[1] * invq3[q];
  const int tid = threadIdx.x;
  float v[15];
  float mx = -1e30f;
  #pragma unroll
  for (int j = 0; j < 15; ++j) {
    int s = tid + j * 256;
    float x = -1e30f;
    if (s < 3600)
      x = c4 * bf2f(r4[s]) * invs4[s] + c3 * bf2f(r3[s]) * invs3[s];
    v[j] = x;
    mx = fmaxf(mx, x);
  }
  #pragma unroll
  for (int o = 32; o > 0; o >>= 1) mx = fmaxf(mx, __shfl_xor(mx, o));
  __shared__ float wmax[4], wsum[4];
  if ((tid & 63) == 0) wmax[tid >> 6] = mx;
  __syncthreads();
  mx = fmaxf(fmaxf(wmax[0], wmax[1]), fmaxf(wmax[2], wmax[3]));
  float sum = 0.f;
  #pragma unroll
  for (int j = 0; j < 15; ++j) {
    int s = tid + j * 256;
    float e = (s < 3600) ? __expf(v[j] - mx) : 0.f;
    v[j] = e;
    sum += e;
  }
  #pragma unroll
  for (int o = 32; o > 0; o >>= 1) sum += __shfl_xor(sum, o);
  if ((tid & 63) == 0) wsum[tid >> 6] = sum;
  __syncthreads();
  sum = wsum[0] + wsum[1] + wsum[2] + wsum[3];
  const float inv448 = 448.0f / sum;
  #pragma unroll
  for (int j = 0; j < 15; ++j) {
    int s = tid + j * 256;
    unsigned char b = (s < 3600) ? f2e4m3(v[j] * inv448) : (unsigned char)0;
    Att[((size_t)(s >> 4) * 3840 + q) * 16 + (s & 15)] = b;
  }
}

// ---------------------------------------------------------------------------
// 6) out[c][p] = 0.5*f_q[c][p] + (0.25/448)*sum_z P[z][p][c]  (3 bf16 partials)
__global__ __launch_bounds__(256) void final_blend_k(
    const unsigned short* __restrict__ P, const float* __restrict__ fq,
    float* __restrict__ out)
{
  __shared__ float t[32][33];
  const int tx = threadIdx.x, ty = threadIdx.y;
  const int p0 = blockIdx.x * 32, c0 = blockIdx.y * 32;
  const long ZC = 3840L * 512;
  #pragma unroll
  for (int i = 0; i < 4; ++i) {
    int p = p0 + ty + i * 8, c = c0 + tx;
    float s = 0.f;
    if (p < 3600) {
      size_t o = (size_t)p * 512 + c;
      #pragma unroll
      for (int z = 0; z < 3; ++z) s += bf2f(P[o + (size_t)z * ZC]);
    }
    t[ty + i * 8][tx] = s;
  }
  __syncthreads();
  const float wts = 0.25f / 448.0f;
  #pragma unroll
  for (int i = 0; i < 4; ++i) {
    int c = c0 + ty + i * 8, p = p0 + tx;
    if (p < 3600) {
      size_t o = (size_t)c * 3600 + p;
      out[o] = 0.5f * fq[o] + wts * t[tx][ty + i * 8];
    }
  }
}

// ---------------------------------------------------------------------------
extern "C" void kernel_launch(void* const* d_in, const int* in_sizes, int n_in,
                              void* d_out, int out_size, void* d_ws, size_t ws_size,
                              hipStream_t stream) {
  const float* fq3 = (const float*)d_in[0];
  const float* fq4 = (const float*)d_in[1];
  const float* fs3 = (const float*)d_in[2];
  const float* fs4 = (const float*)d_in[3];
  const float* f_q = (const float*)d_in[4];
  const float* f_s = (const float*)d_in[5];
  const float* wch = (const float*)d_in[6];
  float* out = (float*)d_out;

  const size_t HW = 3600, MP = 3840, KC = 3072, CH = 512;

  // workspace (~120 MB)
  unsigned char* QT8 = (unsigned char*)d_ws;          // (KC/16, MP, 16B) fp8 query (raw*16)
  unsigned char* ST8 = QT8 + MP * KC;                 // (KC/16, MP, 16B) fp8 support
  unsigned char* V8  = ST8 + MP * KC;                 // (MP/16, CH, 16B) fp8 V
  unsigned short* L4 = (unsigned short*)(V8 + MP * CH);   // (MP,MP) bf16 level-4 dots
  unsigned short* L3 = L4 + MP * MP;                  // (MP,MP) bf16 level-3 dots
  unsigned char* Att8 = (unsigned char*)(L3 + MP * MP);   // (MP/16, MP, 16B) fp8 attn*448
  unsigned short* Pb = (unsigned short*)(Att8 + MP * MP); // 3 x (MP,CH) bf16 partials
  float* invq4 = (float*)(Pb + 3 * MP * CH);          // 4 x 3600 norm inverses
  float* invq3 = invq4 + HW;
  float* invs4 = invq3 + HW;
  float* invs3 = invs4 + HW;
  float* partQ = invs3 + HW;                          // 96 x 3600
  float* partS = partQ + 96 * HW;                     // 96 x 3600

  dim3 tb(32, 8);
  tpose2_f8_k<<<dim3(113, 96), tb, 0, stream>>>(fq4, fq3, QT8, partQ);
  norm_fin_k<<<15, 256, 0, stream>>>(partQ, invq4, invq3);

  const long G4OFF = 128L * MP * 16;   // byte offset of k-group 128 (level-3 cols)

  for (int b = 0; b < 2; ++b) {
    castv_f8_k<<<7200, 256, 0, stream>>>(f_s + (size_t)b * CH * HW, V8);
    tpose2_f8_k<<<dim3(113, 96), tb, 0, stream>>>(
        fs4 + (size_t)b * 2048 * HW, fs3 + (size_t)b * 1024 * HW, ST8, partS);
    norm_fin_k<<<15, 256, 0, stream>>>(partS, invs4, invs3);

    gemm128_f8<<<900, 256, 0, stream>>>(QT8, ST8, L4, 2048, 3840, 3840, 30);
    gemm128_f8<<<900, 256, 0, stream>>>(QT8 + G4OFF, ST8 + G4OFF, L3, 1024, 3840, 3840, 30);

    softmax_rows_k<<<3600, 256, 0, stream>>>(L4, L3, invq4, invq3, invs4, invs3,
                                             wch, Att8);

    // PV split-K=3, deep-pipelined, XCD-chunked (360 blocks)
    pv_f8_k<<<360, 256, 0, stream>>>(Att8, V8, Pb, b);
  }

  final_blend_k<<<dim3(113, 16), tb, 0, stream>>>(Pb, f_q, out);
}

// Round 15
// 264.833 us; speedup vs baseline: 1.2609x; 1.1074x over previous
//
#include <hip/hip_runtime.h>
#include <cstdint>

#define TEMP_C 20.0f
#define FSCALE 16.0f   // fp8 quantization scale (V path)

typedef float f32x4 __attribute__((ext_vector_type(4)));
typedef float f32x16 __attribute__((ext_vector_type(16)));
typedef int i32x4 __attribute__((ext_vector_type(4)));
typedef int i32x8 __attribute__((ext_vector_type(8)));

// fp32 -> bf16 round-to-nearest-even
__device__ __forceinline__ unsigned short f2bf(float f) {
  union { float f; unsigned int u; } v; v.f = f;
  unsigned int r = v.u + 0x7FFFu + ((v.u >> 16) & 1u);
  return (unsigned short)(r >> 16);
}
__device__ __forceinline__ float bf2f(unsigned short b) {
  union { unsigned int u; float f; } v; v.u = ((unsigned int)b) << 16;
  return v.f;
}

// fp32 -> OCP e4m3fn, RTNE, clamp to +-448
__device__ __forceinline__ unsigned char f2e4m3(float f) {
  unsigned u = __float_as_uint(f);
  unsigned s = (u >> 24) & 0x80u;
  float a = fminf(fabsf(f), 448.0f);
  if (a < 0.015625f) {
    int d = (int)rintf(a * 512.0f);
    return (unsigned char)(s | (unsigned)d);
  }
  unsigned au = __float_as_uint(a);
  unsigned r = au + 0xFFFFFu + ((au >> 20) & 1u);
  int Ep = (int)(r >> 23) - 127;
  if (Ep > 8) return (unsigned char)(s | 0x7E);
  unsigned m = (r >> 20) & 7u;
  return (unsigned char)(s | ((unsigned)(Ep + 7) << 3) | m);
}

// fp32 -> e2m1 nibble (round to nearest of {0,.5,1,1.5,2,3,4,6}, sign bit3)
__device__ __forceinline__ unsigned f2e2m1(float f) {
  unsigned s = (__float_as_uint(f) >> 28) & 8u;
  float a = fabsf(f);
  unsigned n = (unsigned)(a >= 0.25f) + (a >= 0.75f) + (a >= 1.25f) +
               (a >= 1.75f) + (a >= 2.5f) + (a >= 3.5f) + (a >= 5.0f);
  return s | n;
}

// async global->LDS, 16B per lane (dest = wave-uniform base + lane*16)
__device__ __forceinline__ void gload_lds16(const void* g, void* l) {
  __builtin_amdgcn_global_load_lds(
      (__attribute__((address_space(1))) void*)(g),
      (__attribute__((address_space(3))) void*)(l), 16, 0, 0);
}

// ---------------------------------------------------------------------------
// 1) fused transpose + FP4 pack + per-(pixel, 32ch-group) sumsq partials.
//    K-GROUP-MAJOR fp4: group g = 32 channels = 16B; byte b = channels
//    2b,2b+1 (lo/hi nibble). T[(g*3840 + p)*16 + b]. Norms post-GEMM.
__global__ __launch_bounds__(256) void tpose2_f4_k(
    const float* __restrict__ X4, const float* __restrict__ X3,
    unsigned char* __restrict__ T, float* __restrict__ part)
{
  __shared__ float tile[32][33];
  __shared__ float red2[8][33];
  const int tx = threadIdx.x, ty = threadIdx.y;
  const int y = blockIdx.y;      // group index g == y (level4: 0..63, level3: 64..95)
  const float* X; int c0;
  if (y < 64) { X = X4; c0 = y * 32; }
  else        { X = X3; c0 = (y - 64) * 32; }
  const int p0 = blockIdx.x * 32;
  #pragma unroll
  for (int i = 0; i < 4; ++i) {
    int c = c0 + ty + i * 8, p = p0 + tx;
    tile[ty + i * 8][tx] = (p < 3600) ? X[(size_t)c * 3600 + p] : 0.f;
  }
  __syncthreads();
  {
    float s = 0.f;
    #pragma unroll
    for (int k = 0; k < 4; ++k) { float v = tile[ty * 4 + k][tx]; s += v * v; }
    red2[ty][tx] = s;
  }
  // fp4 write: threads tx<16 own byte b=tx (channels 2tx, 2tx+1)
  if (tx < 16) {
    const size_t gbase = (size_t)y * 3840 * 16 + tx;
    #pragma unroll
    for (int i = 0; i < 4; ++i) {
      int p = p0 + ty + i * 8;
      if (p < 3600) {
        unsigned lo = f2e2m1(tile[2 * tx][ty + i * 8]);
        unsigned hi = f2e2m1(tile[2 * tx + 1][ty + i * 8]);
        T[gbase + (size_t)p * 16] = (unsigned char)(lo | (hi << 4));
      }
    }
  }
  __syncthreads();
  if (ty == 0 && p0 + tx < 3600) {
    float s = 0.f;
    #pragma unroll
    for (int j = 0; j < 8; ++j) s += red2[j][tx];
    part[(size_t)y * 3600 + p0 + tx] = s;
  }
}

// 1b) finish: inv4[p] = 1/||x4_p||, inv3[p] = 1/||x3_p|| from 96 partials
__global__ __launch_bounds__(256) void norm_fin_k(
    const float* __restrict__ part, float* __restrict__ inv4,
    float* __restrict__ inv3)
{
  const int p = blockIdx.x * 256 + threadIdx.x;
  if (p >= 3600) return;
  float s4 = 0.f, s3 = 0.f;
  #pragma unroll
  for (int y = 0; y < 64; ++y) s4 += part[(size_t)y * 3600 + p];
  #pragma unroll
  for (int y = 64; y < 96; ++y) s3 += part[(size_t)y * 3600 + p];
  inv4[p] = 1.0f / fmaxf(sqrtf(s4), 1e-12f);
  inv3[p] = 1.0f / fmaxf(sqrtf(s3), 1e-12f);
}

// ---------------------------------------------------------------------------
// 2) V cast to fp8, K-group-major over s: V8[((s>>4)*512 + c)*16 + (s&15)]
__global__ void castv_f8_k(const float* __restrict__ X, unsigned char* __restrict__ V8)
{
  int i = blockIdx.x * 256 + threadIdx.x;
  if (i >= 512 * 3600) return;
  int c = i / 3600, s = i - c * 3600;
  V8[((size_t)(s >> 4) * 512 + c) * 16 + (s & 15)] = f2e4m3(X[i]);
}

// ---------------------------------------------------------------------------
// 3) 128x128 MX-FP4 GEMM (r11-verified structure; dtype fp4, BK=128 = 4
//    nibble-groups of 32 elems). Per-tile cost == fp8 BK=64 tile, but HALF
//    the tiles. Frag = 1 b128 (16B = 32 fp4) duplicated into both halves of
//    the v8i32 operand (hedges lo/hi register convention; extra regs unread).
//    cbsz=blgp=4 (FMT fp4). Nibble-order within groups cancels A vs B
//    (same pack convention -> k-permutation invariant dot). Output bf16.
__global__ __launch_bounds__(256, 4) void gemm128_f4(
    const unsigned char* __restrict__ A, const unsigned char* __restrict__ B,
    unsigned short* __restrict__ C, int K, int MPr, int ldc, int nbn)
{
  __shared__ __align__(16) unsigned char As[2][8192];   // [4 g][128 rows][16B]
  __shared__ __align__(16) unsigned char Bs[2][8192];

  const int tid  = threadIdx.x;
  const int lane = tid & 63;
  const int wave = tid >> 6;
  const int wrow = wave >> 1;
  const int wcol = wave & 1;

  const int nwg = gridDim.x;
  const int q8 = nwg >> 3, r8 = nwg & 7;
  const int xcd = blockIdx.x & 7, bidx = blockIdx.x >> 3;
  const int wg = (xcd < r8 ? xcd * (q8 + 1) : r8 * (q8 + 1) + (xcd - r8) * q8) + bidx;
  const long Arow0 = (long)(wg / nbn) * 128;
  const long Brow0 = (long)(wg % nbn) * 128;

  const unsigned char* sA[2];
  const unsigned char* sB[2];
  #pragma unroll
  for (int q = 0; q < 2; ++q) {
    const int c = q * 256 + tid;
    const int g = c >> 7, r = c & 127;
    sA[q] = A + ((long)g * MPr + Arow0 + r) * 16;
    sB[q] = B + ((long)g * MPr + Brow0 + r) * 16;
  }
  const long kstride = (long)MPr * 16 * 4;   // 4 groups (=128 fp4 k) per tile

  #define STAGE(tt) do { const int _sl = (tt) & 1; const long _ko = (long)(tt) * kstride; \
    gload_lds16(sA[0] + _ko, &As[_sl][tid * 16]);              \
    gload_lds16(sA[1] + _ko, &As[_sl][(256 + tid) * 16]);      \
    gload_lds16(sB[0] + _ko, &Bs[_sl][tid * 16]);              \
    gload_lds16(sB[1] + _ko, &Bs[_sl][(256 + tid) * 16]);      \
  } while (0)

  const int l31 = lane & 31, lk = lane >> 5;
  const int arow0 = (wrow * 64 + l31) * 16;   // m=0; m=1 at +512 (32 rows)
  const int brow0 = (wcol * 64 + l31) * 16;

  f32x16 acc[2][2] = {};
  const int NT = K >> 7;   // 128 fp4 k per tile

  STAGE(0);

  for (int t = 0; t < NT; ++t) {
    const int sl = t & 1;
    if (t + 1 < NT) {
      STAGE(t + 1);
      asm volatile("s_waitcnt vmcnt(4)" ::: "memory");  // tile t landed; t+1 in flight
    } else {
      asm volatile("s_waitcnt vmcnt(0)" ::: "memory");
    }
    asm volatile("s_barrier" ::: "memory");

    const unsigned char* Ap = As[sl];
    const unsigned char* Bp = Bs[sl];
    // lane's group for k-half h: g = h*2 + lk; group stride 2048B
    #define FRAG4(dst, base, rowb, g) do {                       \
      i32x4 _v = *(const i32x4*)((base) + ((g) << 11) + (rowb)); \
      dst[0]=_v[0]; dst[1]=_v[1]; dst[2]=_v[2]; dst[3]=_v[3];    \
      dst[4]=_v[0]; dst[5]=_v[1]; dst[6]=_v[2]; dst[7]=_v[3];    \
    } while (0)
    #define MFMA4(a, b, m, n) \
      acc[m][n] = __builtin_amdgcn_mfma_scale_f32_32x32x64_f8f6f4( \
          a, b, acc[m][n], 4, 4, 0, 127, 0, 127)

    #pragma unroll
    for (int h = 0; h < 2; ++h) {
      const int g = h * 2 + lk;
      i32x8 a0, a1, b0, b1;
      FRAG4(a0, Ap, arow0, g); FRAG4(a1, Ap, arow0 + 512, g);
      FRAG4(b0, Bp, brow0, g); FRAG4(b1, Bp, brow0 + 512, g);
      __builtin_amdgcn_s_setprio(1);
      MFMA4(a0, b0, 0, 0); MFMA4(a0, b1, 0, 1);
      MFMA4(a1, b0, 1, 0); MFMA4(a1, b1, 1, 1);
      __builtin_amdgcn_s_setprio(0);
    }
    #undef FRAG4
    #undef MFMA4
    asm volatile("s_barrier" ::: "memory");
  }
  #undef STAGE

  // epilogue (bf16): col=lane&31, row = (reg&3) + 8*(reg>>2) + 4*(lane>>5)
  #pragma unroll
  for (int m = 0; m < 2; ++m) {
    const long rowb = Arow0 + wrow * 64 + m * 32;
    #pragma unroll
    for (int g4 = 0; g4 < 4; ++g4) {
      #pragma unroll
      for (int r4 = 0; r4 < 4; ++r4) {
        const long row = rowb + r4 + 8 * g4 + 4 * lk;
        unsigned short* cp = C + row * (long)ldc + Brow0 + wcol * 64 + l31;
        cp[0]  = f2bf(acc[m][0][g4 * 4 + r4]);
        cp[32] = f2bf(acc[m][1][g4 * 4 + r4]);
      }
    }
  }
}

// ---------------------------------------------------------------------------
// 4) PV MX-fp8 GEMM, deep-pipelined (r14 verified, unchanged).
__global__ __launch_bounds__(256, 2) void pv_f8_k(
    const unsigned char* __restrict__ Att, const unsigned char* __restrict__ V,
    unsigned short* __restrict__ P, int accumulate)
{
  __shared__ __align__(16) unsigned char As[4][4096];
  __shared__ __align__(16) unsigned char As2[4][4096];
  __shared__ __align__(16) unsigned char Bs[4][4096];
  __shared__ __align__(16) unsigned char Bs2[4][4096];

  const int tid  = threadIdx.x;
  const int lane = tid & 63;
  const int wave = tid >> 6;
  const int wrow = wave >> 1;
  const int wcol = wave & 1;

  const int xcd = blockIdx.x & 7, bidx = blockIdx.x >> 3;
  const int wg = xcd * 45 + bidx;
  const int x = wg / 12, rem = wg % 12;
  const int y = rem & 3, z = rem >> 2;
  const long Arow0 = (long)x * 128;
  const long Brow0 = (long)y * 128;
  P += (long)z * 3840 * 512;

  const unsigned char* sA[2];
  const unsigned char* sB[2];
  #pragma unroll
  for (int q = 0; q < 2; ++q) {
    const int c = q * 256 + tid;
    const int g = c >> 7, r = c & 127;
    sA[q] = Att + ((long)(z * 80 + g) * 3840 + Arow0 + r) * 16;
    sB[q] = V   + ((long)(z * 80 + g) * 512  + Brow0 + r) * 16;
  }
  const long ksA = 3840L * 16 * 4;
  const long ksB = 512L * 16 * 4;

  #define STAGE(tt) do { const int _sl = (tt) & 3;                      \
    gload_lds16(sA[0] + (long)(tt) * ksA, &As[_sl][tid * 16]);          \
    gload_lds16(sA[1] + (long)(tt) * ksA, &As2[_sl][tid * 16]);         \
    gload_lds16(sB[0] + (long)(tt) * ksB, &Bs[_sl][tid * 16]);          \
    gload_lds16(sB[1] + (long)(tt) * ksB, &Bs2[_sl][tid * 16]);         \
  } while (0)

  const int l31 = lane & 31, lk = lane >> 5;
  const int arow0 = (wrow * 64 + l31) * 16;
  const int brow0 = (wcol * 64 + l31) * 16;

  f32x16 acc[2][2] = {};
  const int NT = 20;

  STAGE(0); STAGE(1); STAGE(2);

  for (int t = 0; t < NT; ++t) {
    const int sl = t & 3;
    const int rem_t = NT - 1 - t;
    if (rem_t >= 2)      asm volatile("s_waitcnt vmcnt(8)" ::: "memory");
    else if (rem_t == 1) asm volatile("s_waitcnt vmcnt(4)" ::: "memory");
    else                 asm volatile("s_waitcnt vmcnt(0)" ::: "memory");
    asm volatile("s_barrier" ::: "memory");
    if (t + 3 < NT) STAGE(t + 3);

    const unsigned char* ApL = lk ? As2[sl] : As[sl];
    const unsigned char* BpL = lk ? Bs2[sl] : Bs[sl];
    #define LDF(base, rowb, s) (*(const i32x4*)((base) + (((s) << 11) + (rowb))))
    #define FRAG(dst, base, rowb) do {                  \
      i32x4 _lo = LDF(base, rowb, 0);                   \
      i32x4 _hi = LDF(base, rowb, 1);                   \
      dst[0]=_lo[0]; dst[1]=_lo[1]; dst[2]=_lo[2]; dst[3]=_lo[3]; \
      dst[4]=_hi[0]; dst[5]=_hi[1]; dst[6]=_hi[2]; dst[7]=_hi[3]; \
    } while (0)
    #define MFMA8(a, b, m, n) \
      acc[m][n] = __builtin_amdgcn_mfma_scale_f32_32x32x64_f8f6f4( \
          a, b, acc[m][n], 0, 0, 0, 127, 0, 127)

    i32x8 a0, a1, b0, b1;
    FRAG(a0, ApL, arow0); FRAG(a1, ApL, arow0 + 512);
    FRAG(b0, BpL, brow0); FRAG(b1, BpL, brow0 + 512);
    asm volatile("s_waitcnt lgkmcnt(0)" ::: "memory");
    __builtin_amdgcn_sched_barrier(0);
    __builtin_amdgcn_s_setprio(1);
    MFMA8(a0, b0, 0, 0); MFMA8(a0, b1, 0, 1);
    MFMA8(a1, b0, 1, 0); MFMA8(a1, b1, 1, 1);
    __builtin_amdgcn_s_setprio(0);
    #undef LDF
    #undef FRAG
    #undef MFMA8
  }
  #undef STAGE

  #pragma unroll
  for (int m = 0; m < 2; ++m) {
    const long rowb = Arow0 + wrow * 64 + m * 32;
    #pragma unroll
    for (int g4 = 0; g4 < 4; ++g4) {
      #pragma unroll
      for (int r4 = 0; r4 < 4; ++r4) {
        const long row = rowb + r4 + 8 * g4 + 4 * lk;
        unsigned short* cp = P + row * 512 + Brow0 + wcol * 64 + l31;
        float v0 = acc[m][0][g4 * 4 + r4];
        float v1 = acc[m][1][g4 * 4 + r4];
        if (accumulate) { v0 += bf2f(cp[0]); v1 += bf2f(cp[32]); }
        cp[0]  = f2bf(v0);
        cp[32] = f2bf(v1);
      }
    }
  }
}

// ---------------------------------------------------------------------------
// 5) row softmax with POST-GEMM norm application -> fp8 attn*448, K-group-major
__global__ __launch_bounds__(256) void softmax_rows_k(
    const unsigned short* __restrict__ L4, const unsigned short* __restrict__ L3,
    const float* __restrict__ invq4, const float* __restrict__ invq3,
    const float* __restrict__ invs4, const float* __restrict__ invs3,
    const float* __restrict__ wch, unsigned char* __restrict__ Att)
{
  const int q = blockIdx.x;
  const unsigned short* r4 = L4 + (size_t)q * 3840;
  const unsigned short* r3 = L3 + (size_t)q * 3840;
  // fp4 operands are raw features (scale 1): logit = TEMP*w*dot*invq*invs
  const float c4 = TEMP_C * wch[0] * invq4[q];
  const float c3 = TEMP_C * wch[1] * invq3[q];
  const int tid = threadIdx.x;
  float v[15];
  float mx = -1e30f;
  #pragma unroll
  for (int j = 0; j < 15; ++j) {
    int s = tid + j * 256;
    float x = -1e30f;
    if (s < 3600)
      x = c4 * bf2f(r4[s]) * invs4[s] + c3 * bf2f(r3[s]) * invs3[s];
    v[j] = x;
    mx = fmaxf(mx, x);
  }
  #pragma unroll
  for (int o = 32; o > 0; o >>= 1) mx = fmaxf(mx, __shfl_xor(mx, o));
  __shared__ float wmax[4], wsum[4];
  if ((tid & 63) == 0) wmax[tid >> 6] = mx;
  __syncthreads();
  mx = fmaxf(fmaxf(wmax[0], wmax[1]), fmaxf(wmax[2], wmax[3]));
  float sum = 0.f;
  #pragma unroll
  for (int j = 0; j < 15; ++j) {
    int s = tid + j * 256;
    float e = (s < 3600) ? __expf(v[j] - mx) : 0.f;
    v[j] = e;
    sum += e;
  }
  #pragma unroll
  for (int o = 32; o > 0; o >>= 1) sum += __shfl_xor(sum, o);
  if ((tid & 63) == 0) wsum[tid >> 6] = sum;
  __syncthreads();
  sum = wsum[0] + wsum[1] + wsum[2] + wsum[3];
  const float inv448 = 448.0f / sum;
  #pragma unroll
  for (int j = 0; j < 15; ++j) {
    int s = tid + j * 256;
    unsigned char b = (s < 3600) ? f2e4m3(v[j] * inv448) : (unsigned char)0;
    Att[((size_t)(s >> 4) * 3840 + q) * 16 + (s & 15)] = b;
  }
}

// ---------------------------------------------------------------------------
// 6) out[c][p] = 0.5*f_q[c][p] + (0.25/448)*sum_z P[z][p][c]  (3 bf16 partials)
__global__ __launch_bounds__(256) void final_blend_k(
    const unsigned short* __restrict__ P, const float* __restrict__ fq,
    float* __restrict__ out)
{
  __shared__ float t[32][33];
  const int tx = threadIdx.x, ty = threadIdx.y;
  const int p0 = blockIdx.x * 32, c0 = blockIdx.y * 32;
  const long ZC = 3840L * 512;
  #pragma unroll
  for (int i = 0; i < 4; ++i) {
    int p = p0 + ty + i * 8, c = c0 + tx;
    float s = 0.f;
    if (p < 3600) {
      size_t o = (size_t)p * 512 + c;
      #pragma unroll
      for (int z = 0; z < 3; ++z) s += bf2f(P[o + (size_t)z * ZC]);
    }
    t[ty + i * 8][tx] = s;
  }
  __syncthreads();
  const float wts = 0.25f / 448.0f;
  #pragma unroll
  for (int i = 0; i < 4; ++i) {
    int c = c0 + ty + i * 8, p = p0 + tx;
    if (p < 3600) {
      size_t o = (size_t)c * 3600 + p;
      out[o] = 0.5f * fq[o] + wts * t[tx][ty + i * 8];
    }
  }
}

// ---------------------------------------------------------------------------
extern "C" void kernel_launch(void* const* d_in, const int* in_sizes, int n_in,
                              void* d_out, int out_size, void* d_ws, size_t ws_size,
                              hipStream_t stream) {
  const float* fq3 = (const float*)d_in[0];
  const float* fq4 = (const float*)d_in[1];
  const float* fs3 = (const float*)d_in[2];
  const float* fs4 = (const float*)d_in[3];
  const float* f_q = (const float*)d_in[4];
  const float* f_s = (const float*)d_in[5];
  const float* wch = (const float*)d_in[6];
  float* out = (float*)d_out;

  const size_t HW = 3600, MP = 3840, CH = 512;
  const size_t NG = 96;            // fp4 k-groups (32 ch each) across both levels

  // workspace (~108 MB)
  unsigned char* QT4 = (unsigned char*)d_ws;          // (96, MP, 16B) fp4 query (raw)
  unsigned char* ST4 = QT4 + NG * MP * 16;            // (96, MP, 16B) fp4 support
  unsigned char* V8  = ST4 + NG * MP * 16;            // (MP/16, CH, 16B) fp8 V
  unsigned short* L4 = (unsigned short*)(V8 + MP * CH);   // (MP,MP) bf16 level-4 dots
  unsigned short* L3 = L4 + MP * MP;                  // (MP,MP) bf16 level-3 dots
  unsigned char* Att8 = (unsigned char*)(L3 + MP * MP);   // (MP/16, MP, 16B) fp8 attn*448
  unsigned short* Pb = (unsigned short*)(Att8 + MP * MP); // 3 x (MP,CH) bf16 partials
  float* invq4 = (float*)(Pb + 3 * MP * CH);          // 4 x 3600 norm inverses
  float* invq3 = invq4 + HW;
  float* invs4 = invq3 + HW;
  float* invs3 = invs4 + HW;
  float* partQ = invs3 + HW;                          // 96 x 3600
  float* partS = partQ + 96 * HW;                     // 96 x 3600

  dim3 tb(32, 8);
  tpose2_f4_k<<<dim3(113, 96), tb, 0, stream>>>(fq4, fq3, QT4, partQ);
  norm_fin_k<<<15, 256, 0, stream>>>(partQ, invq4, invq3);

  const long G4OFF = 64L * MP * 16;   // byte offset of group 64 (level-3 cols)

  for (int b = 0; b < 2; ++b) {
    castv_f8_k<<<7200, 256, 0, stream>>>(f_s + (size_t)b * CH * HW, V8);
    tpose2_f4_k<<<dim3(113, 96), tb, 0, stream>>>(
        fs4 + (size_t)b * 2048 * HW, fs3 + (size_t)b * 1024 * HW, ST4, partS);
    norm_fin_k<<<15, 256, 0, stream>>>(partS, invs4, invs3);

    // raw dot products per level (bf16), MX-fp4: K counts fp4 elements
    gemm128_f4<<<900, 256, 0, stream>>>(QT4, ST4, L4, 2048, 3840, 3840, 30);
    gemm128_f4<<<900, 256, 0, stream>>>(QT4 + G4OFF, ST4 + G4OFF, L3, 1024, 3840, 3840, 30);

    softmax_rows_k<<<3600, 256, 0, stream>>>(L4, L3, invq4, invq3, invs4, invs3,
                                             wch, Att8);

    // PV split-K=3, deep-pipelined, XCD-chunked (360 blocks)
    pv_f8_k<<<360, 256, 0, stream>>>(Att8, V8, Pb, b);
  }

  final_blend_k<<<dim3(113, 16), tb, 0, stream>>>(Pb, f_q, out);
}